// Round 10
// baseline (230.606 us; speedup 1.0000x reference)
//
#include <hip/hip_runtime.h>
#include <stdint.h>

#define S 64
#define NSQ 32
#define Lc 2048
#define Cc 512
#define Ec 128
#define OUT_H (S*NSQ*Lc)   /* 4194304 */

typedef __bf16 bf16x8 __attribute__((ext_vector_type(8)));
typedef float floatx4 __attribute__((ext_vector_type(4)));

__device__ __forceinline__ unsigned short f2bf(float f){
  union { float f; uint32_t u; } v; v.f = f;
  uint32_t r = v.u + 0x7fffu + ((v.u >> 16) & 1u);
  return (unsigned short)(r >> 16);
}

// XOR-swizzled LDS offset (in shorts) for the x/x2 tile: row-stride 512,
// 16B groups permuted by row&7 -> frag reads hit 32 banks at 2 lanes/bank.
__device__ __forceinline__ int xoff(int row, int cg) {
  return row*512 + (((cg) ^ (row & 7)) << 3);
}

// ---------------------------------------------------------------------------
// k_prep: adapt dots (coalesced row-pair loads + shfl reduce); W1/W2 ->
// MFMA-fragment-packed bf16; zero logdet.   grid 512 x 256
// W1p: frag = ch*32 + o16; elem(lane,j) = W1[o16*16+(lane&15)][ch*32+(lane>>4)*8+j]
// W2p: frag = (k*2+jh)*16 + cc; elem(lane,j) = W2[jh*16+(lane&15)][cc*32+(lane>>4)*8+j][k]
// ---------------------------------------------------------------------------
__global__ void k_prep(const float* __restrict__ emb,
                       const float* __restrict__ Wa, const float* __restrict__ ba,
                       const float* __restrict__ Wb, const float* __restrict__ bb,
                       const float* __restrict__ W1, const float* __restrict__ W2,
                       float* __restrict__ dynW, float* __restrict__ dynB,
                       unsigned short* __restrict__ W1p, unsigned short* __restrict__ W2p,
                       float* __restrict__ out)
{
  __shared__ float embl[Ec];
  int tid = threadIdx.x;
  int b = blockIdx.x;          // 512 blocks, 8 per sample
  int s = b >> 3, g = b & 7;
  if (tid < Ec) embl[tid] = emb[s*Ec + tid];
  __syncthreads();
  // wave-cooperative dots: 2 rows per iteration, fully coalesced loads
  {
    int w = tid >> 6, lane = tid & 63, le = lane & 31, rh = lane >> 5;
    float4 ev = *(const float4*)&embl[le*4];
    int base_o = g*256 + w*64;
    #pragma unroll 4
    for (int p = 0; p < 32; p++) {
      int ro = base_o + p*2 + rh;
      bool isA = ro < 1536;
      const float* rp = isA ? (Wa + ro*Ec) : (Wb + (ro - 1536)*Ec);
      float4 wv = *(const float4*)&rp[le*4];
      float part = wv.x*ev.x + wv.y*ev.y + wv.z*ev.z + wv.w*ev.w;
      part += __shfl_xor(part, 1, 32);
      part += __shfl_xor(part, 2, 32);
      part += __shfl_xor(part, 4, 32);
      part += __shfl_xor(part, 8, 32);
      part += __shfl_xor(part, 16, 32);
      if (le == 0) {
        if (isA) dynW[s*1536 + ro] = part + ba[ro];
        else     dynB[s*Cc + (ro - 1536)] = part + bb[ro - 1536];
      }
    }
  }

  int gtid = b*256 + tid;      // 0..131071
  // W1 pack: 262144 elems, 2 per thread (j pairs)
  {
    int d0 = gtid*2;
    int j0 = d0 & 7;
    int lane = (d0 >> 3) & 63;
    int frag = d0 >> 9;
    int o16 = frag & 31, ch = frag >> 5;
    int oo = o16*16 + (lane & 15);
    int cc = ch*32 + (lane >> 4)*8 + j0;
    float2 wv = *(const float2*)&W1[oo*512 + cc];
    uint32_t packed = (uint32_t)f2bf(wv.x) | ((uint32_t)f2bf(wv.y) << 16);
    ((uint32_t*)W1p)[gtid] = packed;
  }
  // W2 pack: 49152 elems
  if (gtid < 49152) {
    int d = gtid;
    int j = d & 7;
    int lane = (d >> 3) & 63;
    int frag = d >> 9;
    int k = frag >> 5, jh = (frag >> 4) & 1, cc = frag & 15;
    int jj = jh*16 + (lane & 15);
    int c = cc*32 + (lane >> 4)*8 + j;
    W2p[d] = f2bf(W2[jj*1536 + c*3 + k]);
  }
  if (gtid < S) out[OUT_H + gtid] = 0.f;   // logdet accumulators
}

// ---------------------------------------------------------------------------
// k_fused7: 8-wave (512-thr) block per (l-tile, sample); 1 block/CU (~147 KB).
//   stage:  h rows (16x132) + dynW/dynB -> LDS; compute x[128 ll][512 c]
//           bf16 into swizzled xt ONCE.
//   phase A (barrier-free): acc[512 o][128 ll] = W1p @ x; 16 K-chunks;
//           wave = 64-o tile x 128 l  ->  W1p read ONCE per block (557 MB
//           total L2, at bandwidth budget); af double-buffered from L2.
//   epilogue A: relu(acc+b1) -> x2 in xt (zero cols outside [0,2048)).
//   phase B: KW=3 conv via MFMA (W2p from L2, x2 from LDS) -> x3b [128][37].
//   phase C: h1 copy + sigmoid/affine/out + logdet reduce.
// x2 col ll <-> global l = t*126 - 1 + ll; valid conv outputs ll in [1,126].
// ---------------------------------------------------------------------------
__global__ void __launch_bounds__(512, 2) k_fused7(
    const float* __restrict__ h,
    const unsigned short* __restrict__ W1p, const float* __restrict__ b1,
    const unsigned short* __restrict__ W2p, const float* __restrict__ b2,
    const float* __restrict__ dynW, const float* __restrict__ dynB,
    float* __restrict__ out)
{
  extern __shared__ char smem[];
  float* hs  = (float*)smem;                              // [16][132] f32
  float* dws = (float*)(smem + 8448);                     // [1536]
  float* dbs = (float*)(smem + 14592);                    // [512]
  float* x3b = (float*)smem;                              // [128][37] (aliases stage)
  unsigned short* xt = (unsigned short*)(smem + 18944);   // [128][512] swizzled
  float* red = (float*)(smem + 150016);                   // [8]

  int tid = threadIdx.x;
  int t = blockIdx.x, s = blockIdx.y;
  int lb = t*126 - 1;          // global l of x2 col ll=0
  int w = tid >> 6, ln16 = tid & 15, quad = (tid & 63) >> 4;
  int lane8 = (tid & 63)*8;

  const float* hb = h + s*(NSQ*Lc);

  // -------- stage h window + dyn weights --------
  for (int i = tid; i < 16*132; i += 512) {
    int r = i / 132, col = i - r*132;
    int gl = t*126 - 2 + col;                 // h col for x col ll: hs[ll..ll+2]
    hs[i] = ((unsigned)gl < 2048u) ? hb[r*Lc + gl] : 0.f;
  }
  for (int i = tid; i < 1536; i += 512) dws[i] = dynW[s*1536 + i];
  if (tid < 512) dbs[tid] = dynB[s*Cc + tid];
  __syncthreads();

  // -------- compute x once: thread = (cg 0..63, lg 0..7) --------
  {
    int cg = tid & 63, lg = tid >> 6;
    int c8 = cg*8, q = cg >> 2;
    float wvv[24], bxx[8];
    const float4* wp4 = (const float4*)&dws[c8*3];
    #pragma unroll
    for (int i = 0; i < 6; i++) {
      float4 v = wp4[i];
      wvv[4*i] = v.x; wvv[4*i+1] = v.y; wvv[4*i+2] = v.z; wvv[4*i+3] = v.w;
    }
    float4 b0 = *(const float4*)&dbs[c8];
    float4 b4 = *(const float4*)&dbs[c8 + 4];
    bxx[0]=b0.x; bxx[1]=b0.y; bxx[2]=b0.z; bxx[3]=b0.w;
    bxx[4]=b4.x; bxx[5]=b4.y; bxx[6]=b4.z; bxx[7]=b4.w;
    const float* hr = hs + q*132;
    #pragma unroll
    for (int i = 0; i < 16; i++) {
      int ll = lg*16 + i;
      float hm = hr[ll], hc = hr[ll+1], hp = hr[ll+2];
      ushort4 s0, s1;
      s0.x = f2bf(fmaxf(wvv[0]*hm  + wvv[1]*hc  + wvv[2]*hp  + bxx[0], 0.f));
      s0.y = f2bf(fmaxf(wvv[3]*hm  + wvv[4]*hc  + wvv[5]*hp  + bxx[1], 0.f));
      s0.z = f2bf(fmaxf(wvv[6]*hm  + wvv[7]*hc  + wvv[8]*hp  + bxx[2], 0.f));
      s0.w = f2bf(fmaxf(wvv[9]*hm  + wvv[10]*hc + wvv[11]*hp + bxx[3], 0.f));
      s1.x = f2bf(fmaxf(wvv[12]*hm + wvv[13]*hc + wvv[14]*hp + bxx[4], 0.f));
      s1.y = f2bf(fmaxf(wvv[15]*hm + wvv[16]*hc + wvv[17]*hp + bxx[5], 0.f));
      s1.z = f2bf(fmaxf(wvv[18]*hm + wvv[19]*hc + wvv[20]*hp + bxx[6], 0.f));
      s1.w = f2bf(fmaxf(wvv[21]*hm + wvv[22]*hc + wvv[23]*hp + bxx[7], 0.f));
      int off = xoff(ll, cg);
      *(ushort4*)&xt[off] = s0;
      *(ushort4*)&xt[off + 4] = s1;
    }
  }

  floatx4 acc[4][8];
  #pragma unroll
  for (int mi = 0; mi < 4; mi++)
    #pragma unroll
    for (int ni = 0; ni < 8; ni++)
      acc[mi][ni] = (floatx4){0.f,0.f,0.f,0.f};

  #define LOADAF(ch_, AF_) {                                                  \
    _Pragma("unroll")                                                         \
    for (int mi = 0; mi < 4; mi++)                                            \
      (AF_)[mi] = *(const bf16x8*)&W1p[(((ch_)*32 + w*4 + mi) << 9) + lane8]; \
  }

  #define CHUNK(ch_, AFC_, AFN_, PF_) {                                       \
    if (PF_) LOADAF((ch_) + 1, AFN_);                                         \
    _Pragma("unroll")                                                         \
    for (int ni = 0; ni < 8; ni++) {                                          \
      int row_ = ni*16 + ln16;                                                \
      bf16x8 bfr = *(const bf16x8*)&xt[xoff(row_, (ch_)*4 + quad)];           \
      _Pragma("unroll")                                                       \
      for (int mi = 0; mi < 4; mi++)                                          \
        acc[mi][ni] = __builtin_amdgcn_mfma_f32_16x16x32_bf16((AFC_)[mi], bfr, acc[mi][ni], 0, 0, 0); \
    }                                                                         \
  }

  bf16x8 afA[4], afB[4];
  LOADAF(0, afA);
  __syncthreads();   // x ready

  // -------- phase A: 16 K-chunks, barrier-free, af double-buffered --------
  #pragma unroll 1
  for (int cp = 0; cp < 8; cp++) {
    CHUNK(2*cp,     afA, afB, 1);
    CHUNK(2*cp + 1, afB, afA, (cp < 7));
  }
  __syncthreads();   // all x reads done before x2 overwrites the region

  // -------- epilogue A: relu+b1 -> x2 in xt (bf16), zero invalid l --------
  #pragma unroll
  for (int mi = 0; mi < 4; mi++) {
    int o = w*64 + mi*16 + quad*4;
    float4 b1v = *(const float4*)(b1 + o);
    int cg = o >> 3, half = (quad & 1)*4;
    #pragma unroll
    for (int ni = 0; ni < 8; ni++) {
      int ll = ni*16 + ln16;
      int gl = lb + ll;
      ushort4 st;
      if ((unsigned)gl < 2048u) {
        st.x = f2bf(fmaxf(acc[mi][ni][0] + b1v.x, 0.f));
        st.y = f2bf(fmaxf(acc[mi][ni][1] + b1v.y, 0.f));
        st.z = f2bf(fmaxf(acc[mi][ni][2] + b1v.z, 0.f));
        st.w = f2bf(fmaxf(acc[mi][ni][3] + b1v.w, 0.f));
      } else {
        st.x = 0; st.y = 0; st.z = 0; st.w = 0;   // conv2 zero-pad columns
      }
      *(ushort4*)&xt[xoff(ll, cg) + half] = st;
    }
  }
  __syncthreads();

  // -------- phase B: KW=3 conv via MFMA; wave = (jh, nt 0..3) --------
  {
    int jh = w & 1, nt = w >> 1;
    floatx4 ca[2];
    ca[0] = (floatx4){0.f,0.f,0.f,0.f};
    ca[1] = (floatx4){0.f,0.f,0.f,0.f};
    #pragma unroll
    for (int k = 0; k < 3; k++) {
      #pragma unroll
      for (int cc = 0; cc < 16; cc++) {
        bf16x8 a0 = *(const bf16x8*)&W2p[(((k*2 + jh)*16 + cc) << 9) + lane8];
        #pragma unroll
        for (int ni = 0; ni < 2; ni++) {
          int ll = nt*32 + ni*16 + ln16;
          int rr = ll - 1 + k;
          rr = (rr < 0) ? 0 : ((rr > 127) ? 127 : rr);   // edges discarded
          bf16x8 v0 = *(const bf16x8*)&xt[xoff(rr, cc*4 + quad)];
          ca[ni] = __builtin_amdgcn_mfma_f32_16x16x32_bf16(a0, v0, ca[ni], 0, 0, 0);
        }
      }
    }
    float4 b2v = *(const float4*)(b2 + jh*16 + quad*4);
    #pragma unroll
    for (int ni = 0; ni < 2; ni++) {
      int ll = nt*32 + ni*16 + ln16;
      float4 st;
      st.x = ca[ni][0] + b2v.x;
      st.y = ca[ni][1] + b2v.y;
      st.z = ca[ni][2] + b2v.z;
      st.w = ca[ni][3] + b2v.w;
      *(float4*)&x3b[ll*37 + jh*16 + quad*4] = st;
    }
  }
  __syncthreads();

  // -------- phase C: h1 copy + sigmoid/affine/out + logdet --------
  float ld = 0.f;
  #pragma unroll
  for (int i = 0; i < 8; i++) {
    int idx = tid + i*512;           // 0..4095 = (q 0..31) x (ll 0..127)
    int ll = idx & 127, q = idx >> 7;
    int l = lb + ll;                 // = t*126 - 1 + ll
    if (ll >= 1 && ll <= 126 && l < 2048) {
      int gi = s*(NSQ*Lc) + q*Lc + l;
      if (q < 16) {
        out[gi] = h[gi];             // h1 passthrough
      } else {
        float sv = 1.f / (1.f + __expf(-(x3b[ll*37 + (q-16)] + 2.f))) + 1e-7f;
        float mv = x3b[ll*37 + (q-16) + 16];
        out[gi] = sv * (h[gi] + mv);
        ld += __logf(sv);
      }
    }
  }
  #pragma unroll
  for (int off = 32; off > 0; off >>= 1) ld += __shfl_down(ld, off);
  if ((tid & 63) == 0) red[w] = ld;
  __syncthreads();
  if (tid == 0) {
    float tot = 0.f;
    #pragma unroll
    for (int i = 0; i < 8; i++) tot += red[i];
    atomicAdd(&out[OUT_H + s], tot);
  }
}

// ---------------------------------------------------------------------------
extern "C" void kernel_launch(void* const* d_in, const int* in_sizes, int n_in,
                              void* d_out, int out_size, void* d_ws, size_t ws_size,
                              hipStream_t stream) {
  const float* h   = (const float*)d_in[0];
  const float* emb = (const float*)d_in[1];
  const float* Wa  = (const float*)d_in[2];
  const float* ba  = (const float*)d_in[3];
  const float* Wb  = (const float*)d_in[4];
  const float* bb  = (const float*)d_in[5];
  const float* W1  = (const float*)d_in[6];
  const float* b1  = (const float*)d_in[7];
  const float* W2  = (const float*)d_in[8];
  const float* b2  = (const float*)d_in[9];
  float* out = (float*)d_out;
  char* ws = (char*)d_ws;

  float* dynW = (float*)(ws + 0);                          // 384 KiB
  float* dynB = (float*)(ws + 393216);                     // 128 KiB
  unsigned short* W1p = (unsigned short*)(ws + 524288);    // 512 KiB (packed)
  unsigned short* W2p = (unsigned short*)(ws + 1048576);   // 96 KiB (packed)
  if (ws_size < 1179648ull) return;                        // ~1.2 MB needed

  const int smem_bytes = 150048;  // stage/x3b 18944 + xt 131072 + red 32
  (void)hipFuncSetAttribute((const void*)k_fused7,
                            hipFuncAttributeMaxDynamicSharedMemorySize,
                            smem_bytes);

  k_prep<<<512, 256, 0, stream>>>(emb, Wa, ba, Wb, bb, W1, W2,
                                  dynW, dynB, W1p, W2p, out);
  k_fused7<<<dim3(17, 64), 512, smem_bytes, stream>>>(h, W1p, b1, W2p, b2,
                                                      dynW, dynB, out);
}

// Round 11
// 207.566 us; speedup vs baseline: 1.1110x; 1.1110x over previous
//
#include <hip/hip_runtime.h>
#include <stdint.h>

#define S 64
#define NSQ 32
#define Lc 2048
#define Cc 512
#define Ec 128
#define OUT_H (S*NSQ*Lc)   /* 4194304 */

typedef __bf16 bf16x8 __attribute__((ext_vector_type(8)));
typedef float floatx4 __attribute__((ext_vector_type(4)));

__device__ __forceinline__ unsigned short f2bf(float f){
  union { float f; uint32_t u; } v; v.f = f;
  uint32_t r = v.u + 0x7fffu + ((v.u >> 16) & 1u);
  return (unsigned short)(r >> 16);
}

// XOR-swizzled LDS offset (in shorts) for the x/x2 tile: row-stride 512,
// 16B groups permuted by row&7 -> 8-consecutive-lane issue groups hit
// distinct 4-bank groups for frag reads AND x-compute writes.
__device__ __forceinline__ int xoff(int row, int cg) {
  return row*512 + (((cg) ^ (row & 7)) << 3);
}

// ---------------------------------------------------------------------------
// k_prep: adapt dots (coalesced row-pair loads + shfl reduce); W1/W2 ->
// MFMA-fragment-packed bf16; zero logdet.   grid 512 x 256
// W1p: frag = ch*32 + o16; elem(lane,j) = W1[o16*16+(lane&15)][ch*32+(lane>>4)*8+j]
// W2p: frag = (k*2+jh)*16 + cc; elem(lane,j) = W2[jh*16+(lane&15)][cc*32+(lane>>4)*8+j][k]
// ---------------------------------------------------------------------------
__global__ void k_prep(const float* __restrict__ emb,
                       const float* __restrict__ Wa, const float* __restrict__ ba,
                       const float* __restrict__ Wb, const float* __restrict__ bb,
                       const float* __restrict__ W1, const float* __restrict__ W2,
                       float* __restrict__ dynW, float* __restrict__ dynB,
                       unsigned short* __restrict__ W1p, unsigned short* __restrict__ W2p,
                       float* __restrict__ out)
{
  __shared__ float embl[Ec];
  int tid = threadIdx.x;
  int b = blockIdx.x;          // 512 blocks, 8 per sample
  int s = b >> 3, g = b & 7;
  if (tid < Ec) embl[tid] = emb[s*Ec + tid];
  __syncthreads();
  // wave-cooperative dots: 2 rows per iteration, fully coalesced loads
  {
    int w = tid >> 6, lane = tid & 63, le = lane & 31, rh = lane >> 5;
    float4 ev = *(const float4*)&embl[le*4];
    int base_o = g*256 + w*64;
    #pragma unroll 4
    for (int p = 0; p < 32; p++) {
      int ro = base_o + p*2 + rh;
      bool isA = ro < 1536;
      const float* rp = isA ? (Wa + ro*Ec) : (Wb + (ro - 1536)*Ec);
      float4 wv = *(const float4*)&rp[le*4];
      float part = wv.x*ev.x + wv.y*ev.y + wv.z*ev.z + wv.w*ev.w;
      part += __shfl_xor(part, 1, 32);
      part += __shfl_xor(part, 2, 32);
      part += __shfl_xor(part, 4, 32);
      part += __shfl_xor(part, 8, 32);
      part += __shfl_xor(part, 16, 32);
      if (le == 0) {
        if (isA) dynW[s*1536 + ro] = part + ba[ro];
        else     dynB[s*Cc + (ro - 1536)] = part + bb[ro - 1536];
      }
    }
  }

  int gtid = b*256 + tid;      // 0..131071
  // W1 pack: 262144 elems, 2 per thread (j pairs)
  {
    int d0 = gtid*2;
    int j0 = d0 & 7;
    int lane = (d0 >> 3) & 63;
    int frag = d0 >> 9;
    int o16 = frag & 31, ch = frag >> 5;
    int oo = o16*16 + (lane & 15);
    int cc = ch*32 + (lane >> 4)*8 + j0;
    float2 wv = *(const float2*)&W1[oo*512 + cc];
    uint32_t packed = (uint32_t)f2bf(wv.x) | ((uint32_t)f2bf(wv.y) << 16);
    ((uint32_t*)W1p)[gtid] = packed;
  }
  // W2 pack: 49152 elems
  if (gtid < 49152) {
    int d = gtid;
    int j = d & 7;
    int lane = (d >> 3) & 63;
    int frag = d >> 9;
    int k = frag >> 5, jh = (frag >> 4) & 1, cc = frag & 15;
    int jj = jh*16 + (lane & 15);
    int c = cc*32 + (lane >> 4)*8 + j;
    W2p[d] = f2bf(W2[jj*1536 + c*3 + k]);
  }
  if (gtid < S) out[OUT_H + gtid] = 0.f;   // logdet accumulators
}

// ---------------------------------------------------------------------------
// k_fused8: 8-wave (512-thr) block per (l-tile, sample); 2 blocks/CU,
// 4 waves/SIMD (acc 64 AGPR + ~60 arch VGPR -> 128-reg bucket).
//   stage:  h rows (16x68) + dynW/dynB -> LDS; compute x[64 ll][512 c]
//           bf16 into swizzled xt ONCE (threads = 64 cg x 8 lg).
//   phase A (barrier-free): acc[512 o][64 ll] = W1p @ x; 16 K-chunks;
//           wave = 64-o tile; af (4 frags) double-buffered from L2.
//   epilogue A: relu(acc+b1) -> x2 in xt (zero cols outside [0,2048)).
//   phase B: KW=3 conv via MFMA (W2p from L2, x2 from LDS) -> x3b [64][37].
//   phase C: h1 copy + sigmoid/affine/out + logdet reduce.
// x2 col ll <-> global l = t*62 - 1 + ll; valid outputs ll in [1,62].
// ---------------------------------------------------------------------------
__global__ void __launch_bounds__(512, 4) k_fused8(
    const float* __restrict__ h,
    const unsigned short* __restrict__ W1p, const float* __restrict__ b1,
    const unsigned short* __restrict__ W2p, const float* __restrict__ b2,
    const float* __restrict__ dynW, const float* __restrict__ dynB,
    float* __restrict__ out)
{
  extern __shared__ char smem[];
  float* hs  = (float*)smem;                              // [16][68] f32
  float* dws = (float*)(smem + 4352);                     // [1536]
  float* dbs = (float*)(smem + 10496);                    // [512]
  float* x3b = (float*)smem;                              // [64][37] (aliases stage)
  unsigned short* xt = (unsigned short*)(smem + 12544);   // [64][512] swizzled
  float* red = (float*)(smem + 78080);                    // [8]

  int tid = threadIdx.x;
  int t = blockIdx.x, s = blockIdx.y;
  int lb = t*62 - 1;           // global l of x2 col ll=0
  int w = tid >> 6, ln16 = tid & 15, quad = (tid & 63) >> 4;
  int lane8 = (tid & 63)*8;

  const float* hb = h + s*(NSQ*Lc);

  // -------- stage h window + dyn weights --------
  for (int i = tid; i < 16*68; i += 512) {
    int r = i / 68, col = i - r*68;
    int gl = t*62 - 2 + col;                  // x col ll uses hs[ll..ll+2]
    hs[i] = ((unsigned)gl < 2048u) ? hb[r*Lc + gl] : 0.f;
  }
  for (int i = tid; i < 1536; i += 512) dws[i] = dynW[s*1536 + i];
  if (tid < 512) dbs[tid] = dynB[s*Cc + tid];
  __syncthreads();

  // -------- compute x once: thread = (cg 0..63, lg=w 0..7), 8 cols --------
  {
    int cg = tid & 63;
    int c8 = cg*8, q = cg >> 2;
    float wvv[24], bxx[8];
    const float4* wp4 = (const float4*)&dws[c8*3];
    #pragma unroll
    for (int i = 0; i < 6; i++) {
      float4 v = wp4[i];
      wvv[4*i] = v.x; wvv[4*i+1] = v.y; wvv[4*i+2] = v.z; wvv[4*i+3] = v.w;
    }
    float4 b0 = *(const float4*)&dbs[c8];
    float4 b4 = *(const float4*)&dbs[c8 + 4];
    bxx[0]=b0.x; bxx[1]=b0.y; bxx[2]=b0.z; bxx[3]=b0.w;
    bxx[4]=b4.x; bxx[5]=b4.y; bxx[6]=b4.z; bxx[7]=b4.w;
    const float* hr = hs + q*68;
    int ll0 = w*8;
    float hm = hr[ll0], hc = hr[ll0+1];
    #pragma unroll
    for (int i = 0; i < 8; i++) {
      int ll = ll0 + i;
      float hp = hr[ll+2];
      ushort4 s0, s1;
      s0.x = f2bf(fmaxf(wvv[0]*hm  + wvv[1]*hc  + wvv[2]*hp  + bxx[0], 0.f));
      s0.y = f2bf(fmaxf(wvv[3]*hm  + wvv[4]*hc  + wvv[5]*hp  + bxx[1], 0.f));
      s0.z = f2bf(fmaxf(wvv[6]*hm  + wvv[7]*hc  + wvv[8]*hp  + bxx[2], 0.f));
      s0.w = f2bf(fmaxf(wvv[9]*hm  + wvv[10]*hc + wvv[11]*hp + bxx[3], 0.f));
      s1.x = f2bf(fmaxf(wvv[12]*hm + wvv[13]*hc + wvv[14]*hp + bxx[4], 0.f));
      s1.y = f2bf(fmaxf(wvv[15]*hm + wvv[16]*hc + wvv[17]*hp + bxx[5], 0.f));
      s1.z = f2bf(fmaxf(wvv[18]*hm + wvv[19]*hc + wvv[20]*hp + bxx[6], 0.f));
      s1.w = f2bf(fmaxf(wvv[21]*hm + wvv[22]*hc + wvv[23]*hp + bxx[7], 0.f));
      int off = xoff(ll, cg);
      *(ushort4*)&xt[off] = s0;
      *(ushort4*)&xt[off + 4] = s1;
      hm = hc; hc = hp;
    }
  }

  floatx4 acc[4][4];
  #pragma unroll
  for (int mi = 0; mi < 4; mi++)
    #pragma unroll
    for (int ni = 0; ni < 4; ni++)
      acc[mi][ni] = (floatx4){0.f,0.f,0.f,0.f};

  #define LOADAF(ch_, AF_) {                                                  \
    _Pragma("unroll")                                                         \
    for (int mi = 0; mi < 4; mi++)                                            \
      (AF_)[mi] = *(const bf16x8*)&W1p[(((ch_)*32 + w*4 + mi) << 9) + lane8]; \
  }

  #define CHUNK(ch_, AFC_, AFN_, PF_) {                                       \
    if (PF_) LOADAF((ch_) + 1, AFN_);                                         \
    _Pragma("unroll")                                                         \
    for (int ni = 0; ni < 4; ni++) {                                          \
      bf16x8 bfr = *(const bf16x8*)&xt[xoff(ni*16 + ln16, (ch_)*4 + quad)];   \
      _Pragma("unroll")                                                       \
      for (int mi = 0; mi < 4; mi++)                                          \
        acc[mi][ni] = __builtin_amdgcn_mfma_f32_16x16x32_bf16((AFC_)[mi], bfr, acc[mi][ni], 0, 0, 0); \
    }                                                                         \
  }

  bf16x8 afA[4], afB[4];
  LOADAF(0, afA);
  __syncthreads();   // x ready

  // -------- phase A: 16 K-chunks, barrier-free, af double-buffered --------
  #pragma unroll 1
  for (int cp = 0; cp < 8; cp++) {
    CHUNK(2*cp,     afA, afB, 1);
    CHUNK(2*cp + 1, afB, afA, (cp < 7));
  }
  __syncthreads();   // all x reads done before x2 overwrites the region

  // -------- epilogue A: relu+b1 -> x2 in xt (bf16), zero invalid l --------
  #pragma unroll
  for (int mi = 0; mi < 4; mi++) {
    int o = w*64 + mi*16 + quad*4;
    float4 b1v = *(const float4*)(b1 + o);
    int cg = o >> 3, half = (quad & 1)*4;
    #pragma unroll
    for (int ni = 0; ni < 4; ni++) {
      int ll = ni*16 + ln16;
      int gl = lb + ll;
      ushort4 st;
      if ((unsigned)gl < 2048u) {
        st.x = f2bf(fmaxf(acc[mi][ni][0] + b1v.x, 0.f));
        st.y = f2bf(fmaxf(acc[mi][ni][1] + b1v.y, 0.f));
        st.z = f2bf(fmaxf(acc[mi][ni][2] + b1v.z, 0.f));
        st.w = f2bf(fmaxf(acc[mi][ni][3] + b1v.w, 0.f));
      } else {
        st.x = 0; st.y = 0; st.z = 0; st.w = 0;   // conv2 zero-pad columns
      }
      *(ushort4*)&xt[xoff(ll, cg) + half] = st;
    }
  }
  __syncthreads();

  // -------- phase B: KW=3 conv via MFMA; wave = (jh, nt 0..3) --------
  {
    int jh = w & 1, nt = w >> 1;
    floatx4 ca = (floatx4){0.f,0.f,0.f,0.f};
    int ll = nt*16 + ln16;
    #pragma unroll
    for (int k = 0; k < 3; k++) {
      int rr = ll - 1 + k;
      rr = (rr < 0) ? 0 : ((rr > 63) ? 63 : rr);   // edges discarded
      #pragma unroll
      for (int cc = 0; cc < 16; cc++) {
        bf16x8 a0 = *(const bf16x8*)&W2p[(((k*2 + jh)*16 + cc) << 9) + lane8];
        bf16x8 v0 = *(const bf16x8*)&xt[xoff(rr, cc*4 + quad)];
        ca = __builtin_amdgcn_mfma_f32_16x16x32_bf16(a0, v0, ca, 0, 0, 0);
      }
    }
    float4 b2v = *(const float4*)(b2 + jh*16 + quad*4);
    float4 st;
    st.x = ca[0] + b2v.x;
    st.y = ca[1] + b2v.y;
    st.z = ca[2] + b2v.z;
    st.w = ca[3] + b2v.w;
    *(float4*)&x3b[ll*37 + jh*16 + quad*4] = st;
  }
  __syncthreads();

  // -------- phase C: h1 copy + sigmoid/affine/out + logdet --------
  float ld = 0.f;
  #pragma unroll
  for (int i = 0; i < 4; i++) {
    int idx = tid + i*512;           // 0..2047 = (q 0..31) x (ll 0..63)
    int ll = idx & 63, q = idx >> 6;
    int l = lb + ll;                 // = t*62 - 1 + ll
    if (ll >= 1 && ll <= 62 && l < 2048) {
      int gi = s*(NSQ*Lc) + q*Lc + l;
      if (q < 16) {
        out[gi] = h[gi];             // h1 passthrough
      } else {
        float sv = 1.f / (1.f + __expf(-(x3b[ll*37 + (q-16)] + 2.f))) + 1e-7f;
        float mv = x3b[ll*37 + (q-16) + 16];
        out[gi] = sv * (h[gi] + mv);
        ld += __logf(sv);
      }
    }
  }
  #pragma unroll
  for (int off = 32; off > 0; off >>= 1) ld += __shfl_down(ld, off);
  if ((tid & 63) == 0) red[w] = ld;
  __syncthreads();
  if (tid == 0) {
    float tot = 0.f;
    #pragma unroll
    for (int i = 0; i < 8; i++) tot += red[i];
    atomicAdd(&out[OUT_H + s], tot);
  }
}

// ---------------------------------------------------------------------------
extern "C" void kernel_launch(void* const* d_in, const int* in_sizes, int n_in,
                              void* d_out, int out_size, void* d_ws, size_t ws_size,
                              hipStream_t stream) {
  const float* h   = (const float*)d_in[0];
  const float* emb = (const float*)d_in[1];
  const float* Wa  = (const float*)d_in[2];
  const float* ba  = (const float*)d_in[3];
  const float* Wb  = (const float*)d_in[4];
  const float* bb  = (const float*)d_in[5];
  const float* W1  = (const float*)d_in[6];
  const float* b1  = (const float*)d_in[7];
  const float* W2  = (const float*)d_in[8];
  const float* b2  = (const float*)d_in[9];
  float* out = (float*)d_out;
  char* ws = (char*)d_ws;

  float* dynW = (float*)(ws + 0);                          // 384 KiB
  float* dynB = (float*)(ws + 393216);                     // 128 KiB
  unsigned short* W1p = (unsigned short*)(ws + 524288);    // 512 KiB (packed)
  unsigned short* W2p = (unsigned short*)(ws + 1048576);   // 96 KiB (packed)
  if (ws_size < 1179648ull) return;                        // ~1.2 MB needed

  const int smem_bytes = 78112;  // stage/x3b 12544 + xt 65536 + red 32
  (void)hipFuncSetAttribute((const void*)k_fused8,
                            hipFuncAttributeMaxDynamicSharedMemorySize,
                            smem_bytes);

  k_prep<<<512, 256, 0, stream>>>(emb, Wa, ba, Wb, bb, W1, W2,
                                  dynW, dynB, W1p, W2p, out);
  k_fused8<<<dim3(34, 64), 512, smem_bytes, stream>>>(h, W1p, b1, W2p, b2,
                                                      dynW, dynB, out);
}

// Round 12
// 202.857 us; speedup vs baseline: 1.1368x; 1.0232x over previous
//
#include <hip/hip_runtime.h>
#include <stdint.h>

#define S 64
#define NSQ 32
#define Lc 2048
#define Cc 512
#define Ec 128
#define OUT_H (S*NSQ*Lc)   /* 4194304 */

typedef __bf16 bf16x8 __attribute__((ext_vector_type(8)));
typedef float floatx4 __attribute__((ext_vector_type(4)));

__device__ __forceinline__ unsigned short f2bf(float f){
  union { float f; uint32_t u; } v; v.f = f;
  uint32_t r = v.u + 0x7fffu + ((v.u >> 16) & 1u);
  return (unsigned short)(r >> 16);
}

// XOR-swizzled LDS offset (shorts) for the x/x2 tile (row stride 512).
__device__ __forceinline__ int xoff(int row, int cg) {
  return row*512 + (((cg) ^ (row & 7)) << 3);
}

// ---------------------------------------------------------------------------
// k_prep: adapt dots (coalesced + shfl reduce); W1/W2 -> MFMA-fragment-packed
// bf16; zero logdet.   grid 512 x 256
// W1p: frag = ch*32 + o16; elem(lane,j) = W1[o16*16+(lane&15)][ch*32+(lane>>4)*8+j]
// W2p: frag = (k*2+jh)*16 + cc; elem(lane,j) = W2[jh*16+(lane&15)][cc*32+(lane>>4)*8+j][k]
// ---------------------------------------------------------------------------
__global__ void k_prep(const float* __restrict__ emb,
                       const float* __restrict__ Wa, const float* __restrict__ ba,
                       const float* __restrict__ Wb, const float* __restrict__ bb,
                       const float* __restrict__ W1, const float* __restrict__ W2,
                       float* __restrict__ dynW, float* __restrict__ dynB,
                       unsigned short* __restrict__ W1p, unsigned short* __restrict__ W2p,
                       float* __restrict__ out)
{
  __shared__ float embl[Ec];
  int tid = threadIdx.x;
  int b = blockIdx.x;          // 512 blocks, 8 per sample
  int s = b >> 3, g = b & 7;
  if (tid < Ec) embl[tid] = emb[s*Ec + tid];
  __syncthreads();
  {
    int w = tid >> 6, lane = tid & 63, le = lane & 31, rh = lane >> 5;
    float4 ev = *(const float4*)&embl[le*4];
    int base_o = g*256 + w*64;
    #pragma unroll 4
    for (int p = 0; p < 32; p++) {
      int ro = base_o + p*2 + rh;
      bool isA = ro < 1536;
      const float* rp = isA ? (Wa + ro*Ec) : (Wb + (ro - 1536)*Ec);
      float4 wv = *(const float4*)&rp[le*4];
      float part = wv.x*ev.x + wv.y*ev.y + wv.z*ev.z + wv.w*ev.w;
      part += __shfl_xor(part, 1, 32);
      part += __shfl_xor(part, 2, 32);
      part += __shfl_xor(part, 4, 32);
      part += __shfl_xor(part, 8, 32);
      part += __shfl_xor(part, 16, 32);
      if (le == 0) {
        if (isA) dynW[s*1536 + ro] = part + ba[ro];
        else     dynB[s*Cc + (ro - 1536)] = part + bb[ro - 1536];
      }
    }
  }

  int gtid = b*256 + tid;      // 0..131071
  // W1 pack: 262144 elems, 2 per thread (j pairs)
  {
    int d0 = gtid*2;
    int j0 = d0 & 7;
    int lane = (d0 >> 3) & 63;
    int frag = d0 >> 9;
    int o16 = frag & 31, ch = frag >> 5;
    int oo = o16*16 + (lane & 15);
    int cc = ch*32 + (lane >> 4)*8 + j0;
    float2 wv = *(const float2*)&W1[oo*512 + cc];
    uint32_t packed = (uint32_t)f2bf(wv.x) | ((uint32_t)f2bf(wv.y) << 16);
    ((uint32_t*)W1p)[gtid] = packed;
  }
  // W2 pack: 49152 elems
  if (gtid < 49152) {
    int d = gtid;
    int j = d & 7;
    int lane = (d >> 3) & 63;
    int frag = d >> 9;
    int k = frag >> 5, jh = (frag >> 4) & 1, cc = frag & 15;
    int jj = jh*16 + (lane & 15);
    int c = cc*32 + (lane >> 4)*8 + j;
    W2p[d] = f2bf(W2[jj*1536 + c*3 + k]);
  }
  if (gtid < S) out[OUT_H + gtid] = 0.f;   // logdet accumulators
}

// ---------------------------------------------------------------------------
// k_fused9: 8-wave (512-thr) block per (l-tile, sample); 2 blocks/CU,
// 4 waves/SIMD.  Changes vs R11: phase B dedup (4 waves, both jh each, 96
// MFMA per 48 ds_reads); waves 4-7 do the h1 copy during phase B; phase C
// handles only h2 rows; CHUNK batches its 4 ds_reads before the MFMAs.
// x2 col ll <-> global l = t*62 - 1 + ll; valid outputs ll in [1,62].
// ---------------------------------------------------------------------------
__global__ void __launch_bounds__(512, 4) k_fused9(
    const float* __restrict__ h,
    const unsigned short* __restrict__ W1p, const float* __restrict__ b1,
    const unsigned short* __restrict__ W2p, const float* __restrict__ b2,
    const float* __restrict__ dynW, const float* __restrict__ dynB,
    float* __restrict__ out)
{
  extern __shared__ char smem[];
  float* hs  = (float*)smem;                              // [16][68] f32
  float* dws = (float*)(smem + 4352);                     // [1536]
  float* dbs = (float*)(smem + 10496);                    // [512]
  float* x3b = (float*)smem;                              // [64][37] (aliases stage)
  unsigned short* xt = (unsigned short*)(smem + 12544);   // [64][512] swizzled
  float* red = (float*)(smem + 78080);                    // [8]

  int tid = threadIdx.x;
  int t = blockIdx.x, s = blockIdx.y;
  int lb = t*62 - 1;           // global l of x2 col ll=0
  int w = tid >> 6, ln16 = tid & 15, quad = (tid & 63) >> 4;
  int lane8 = (tid & 63)*8;

  const float* hb = h + s*(NSQ*Lc);

  // -------- stage h window + dyn weights --------
  for (int i = tid; i < 16*68; i += 512) {
    int r = i / 68, col = i - r*68;
    int gl = t*62 - 2 + col;                  // x col ll uses hs[ll..ll+2]
    hs[i] = ((unsigned)gl < 2048u) ? hb[r*Lc + gl] : 0.f;
  }
  for (int i = tid; i < 1536; i += 512) dws[i] = dynW[s*1536 + i];
  if (tid < 512) dbs[tid] = dynB[s*Cc + tid];

  #define LOADAF(ch_, AF_) {                                                  \
    _Pragma("unroll")                                                         \
    for (int mi = 0; mi < 4; mi++)                                            \
      (AF_)[mi] = *(const bf16x8*)&W1p[(((ch_)*32 + w*4 + mi) << 9) + lane8]; \
  }

  bf16x8 afA[4], afB[4];
  LOADAF(0, afA);              // overlap with x-compute below
  __syncthreads();

  // -------- compute x once: thread = (cg 0..63, lg=w 0..7), 8 cols --------
  {
    int cg = tid & 63;
    int c8 = cg*8, q = cg >> 2;
    float wvv[24], bxx[8];
    const float4* wp4 = (const float4*)&dws[c8*3];
    #pragma unroll
    for (int i = 0; i < 6; i++) {
      float4 v = wp4[i];
      wvv[4*i] = v.x; wvv[4*i+1] = v.y; wvv[4*i+2] = v.z; wvv[4*i+3] = v.w;
    }
    float4 b0 = *(const float4*)&dbs[c8];
    float4 b4 = *(const float4*)&dbs[c8 + 4];
    bxx[0]=b0.x; bxx[1]=b0.y; bxx[2]=b0.z; bxx[3]=b0.w;
    bxx[4]=b4.x; bxx[5]=b4.y; bxx[6]=b4.z; bxx[7]=b4.w;
    const float* hr = hs + q*68;
    int ll0 = w*8;
    float hm = hr[ll0], hc = hr[ll0+1];
    #pragma unroll
    for (int i = 0; i < 8; i++) {
      int ll = ll0 + i;
      float hp = hr[ll+2];
      ushort4 s0, s1;
      s0.x = f2bf(fmaxf(wvv[0]*hm  + wvv[1]*hc  + wvv[2]*hp  + bxx[0], 0.f));
      s0.y = f2bf(fmaxf(wvv[3]*hm  + wvv[4]*hc  + wvv[5]*hp  + bxx[1], 0.f));
      s0.z = f2bf(fmaxf(wvv[6]*hm  + wvv[7]*hc  + wvv[8]*hp  + bxx[2], 0.f));
      s0.w = f2bf(fmaxf(wvv[9]*hm  + wvv[10]*hc + wvv[11]*hp + bxx[3], 0.f));
      s1.x = f2bf(fmaxf(wvv[12]*hm + wvv[13]*hc + wvv[14]*hp + bxx[4], 0.f));
      s1.y = f2bf(fmaxf(wvv[15]*hm + wvv[16]*hc + wvv[17]*hp + bxx[5], 0.f));
      s1.z = f2bf(fmaxf(wvv[18]*hm + wvv[19]*hc + wvv[20]*hp + bxx[6], 0.f));
      s1.w = f2bf(fmaxf(wvv[21]*hm + wvv[22]*hc + wvv[23]*hp + bxx[7], 0.f));
      int off = xoff(ll, cg);
      *(ushort4*)&xt[off] = s0;
      *(ushort4*)&xt[off + 4] = s1;
      hm = hc; hc = hp;
    }
  }

  floatx4 acc[4][4];
  #pragma unroll
  for (int mi = 0; mi < 4; mi++)
    #pragma unroll
    for (int ni = 0; ni < 4; ni++)
      acc[mi][ni] = (floatx4){0.f,0.f,0.f,0.f};

  #define CHUNK(ch_, AFC_, AFN_, PF_) {                                       \
    if (PF_) LOADAF((ch_) + 1, AFN_);                                         \
    bf16x8 bfr[4];                                                            \
    _Pragma("unroll")                                                         \
    for (int ni = 0; ni < 4; ni++)                                            \
      bfr[ni] = *(const bf16x8*)&xt[xoff(ni*16 + ln16, (ch_)*4 + quad)];      \
    _Pragma("unroll")                                                         \
    for (int ni = 0; ni < 4; ni++)                                            \
      _Pragma("unroll")                                                       \
      for (int mi = 0; mi < 4; mi++)                                          \
        acc[mi][ni] = __builtin_amdgcn_mfma_f32_16x16x32_bf16((AFC_)[mi], bfr[ni], acc[mi][ni], 0, 0, 0); \
  }

  __syncthreads();   // x ready

  // -------- phase A: 16 K-chunks, barrier-free, af double-buffered --------
  #pragma unroll 1
  for (int cp = 0; cp < 8; cp++) {
    CHUNK(2*cp,     afA, afB, 1);
    CHUNK(2*cp + 1, afB, afA, (cp < 7));
  }
  __syncthreads();   // all x reads done before x2 overwrites the region

  // -------- epilogue A: relu+b1 -> x2 in xt (bf16), zero invalid l --------
  #pragma unroll
  for (int mi = 0; mi < 4; mi++) {
    int o = w*64 + mi*16 + quad*4;
    float4 b1v = *(const float4*)(b1 + o);
    int cg = o >> 3, half = (quad & 1)*4;
    #pragma unroll
    for (int ni = 0; ni < 4; ni++) {
      int ll = ni*16 + ln16;
      int gl = lb + ll;
      ushort4 st;
      if ((unsigned)gl < 2048u) {
        st.x = f2bf(fmaxf(acc[mi][ni][0] + b1v.x, 0.f));
        st.y = f2bf(fmaxf(acc[mi][ni][1] + b1v.y, 0.f));
        st.z = f2bf(fmaxf(acc[mi][ni][2] + b1v.z, 0.f));
        st.w = f2bf(fmaxf(acc[mi][ni][3] + b1v.w, 0.f));
      } else {
        st.x = 0; st.y = 0; st.z = 0; st.w = 0;   // conv2 zero-pad columns
      }
      *(ushort4*)&xt[xoff(ll, cg) + half] = st;
    }
  }
  __syncthreads();

  // -------- phase B: waves 0-3 conv (both jh); waves 4-7 h1 copy --------
  if (w < 4) {
    floatx4 ca0 = (floatx4){0.f,0.f,0.f,0.f};
    floatx4 ca1 = (floatx4){0.f,0.f,0.f,0.f};
    int ll = w*16 + ln16;
    #pragma unroll
    for (int k = 0; k < 3; k++) {
      int rr = ll - 1 + k;
      rr = (rr < 0) ? 0 : ((rr > 63) ? 63 : rr);   // edges discarded
      #pragma unroll
      for (int cc = 0; cc < 16; cc++) {
        bf16x8 v0 = *(const bf16x8*)&xt[xoff(rr, cc*4 + quad)];
        bf16x8 a0 = *(const bf16x8*)&W2p[(((k*2 + 0)*16 + cc) << 9) + lane8];
        ca0 = __builtin_amdgcn_mfma_f32_16x16x32_bf16(a0, v0, ca0, 0, 0, 0);
        bf16x8 a1 = *(const bf16x8*)&W2p[(((k*2 + 1)*16 + cc) << 9) + lane8];
        ca1 = __builtin_amdgcn_mfma_f32_16x16x32_bf16(a1, v0, ca1, 0, 0, 0);
      }
    }
    float4 b2v0 = *(const float4*)(b2 + quad*4);
    float4 b2v1 = *(const float4*)(b2 + 16 + quad*4);
    float4 st0, st1;
    st0.x = ca0[0] + b2v0.x; st0.y = ca0[1] + b2v0.y;
    st0.z = ca0[2] + b2v0.z; st0.w = ca0[3] + b2v0.w;
    st1.x = ca1[0] + b2v1.x; st1.y = ca1[1] + b2v1.y;
    st1.z = ca1[2] + b2v1.z; st1.w = ca1[3] + b2v1.w;
    *(float4*)&x3b[ll*37 + quad*4] = st0;
    *(float4*)&x3b[ll*37 + 16 + quad*4] = st1;
  } else {
    // h1 passthrough: rows q 0..15, cols l = lb+1 .. lb+62
    int lane = tid & 63;
    int base = (w - 4)*64 + lane;          // 0..255
    #pragma unroll
    for (int i = 0; i < 4; i++) {
      int idx = base + i*256;              // 0..1023 = (q 0..15) x (ll 0..63)
      int ll = idx & 63, q = idx >> 6;
      int l = lb + ll;
      if (ll >= 1 && ll <= 62 && l < 2048) {
        int gi = s*(NSQ*Lc) + q*Lc + l;
        out[gi] = h[gi];
      }
    }
  }
  __syncthreads();

  // -------- phase C: h2 rows only: sigmoid/affine/out + logdet --------
  float ld = 0.f;
  #pragma unroll
  for (int i = 0; i < 2; i++) {
    int idx = tid + i*512;           // 0..1023 = (q16 0..15) x (ll 0..63)
    int ll = idx & 63, q = 16 + (idx >> 6);
    int l = lb + ll;
    if (ll >= 1 && ll <= 62 && l < 2048) {
      int gi = s*(NSQ*Lc) + q*Lc + l;
      float sv = 1.f / (1.f + __expf(-(x3b[ll*37 + (q-16)] + 2.f))) + 1e-7f;
      float mv = x3b[ll*37 + (q-16) + 16];
      out[gi] = sv * (h[gi] + mv);
      ld += __logf(sv);
    }
  }
  #pragma unroll
  for (int off = 32; off > 0; off >>= 1) ld += __shfl_down(ld, off);
  if ((tid & 63) == 0) red[w] = ld;
  __syncthreads();
  if (tid == 0) {
    float tot = 0.f;
    #pragma unroll
    for (int i = 0; i < 8; i++) tot += red[i];
    atomicAdd(&out[OUT_H + s], tot);
  }
}

// ---------------------------------------------------------------------------
extern "C" void kernel_launch(void* const* d_in, const int* in_sizes, int n_in,
                              void* d_out, int out_size, void* d_ws, size_t ws_size,
                              hipStream_t stream) {
  const float* h   = (const float*)d_in[0];
  const float* emb = (const float*)d_in[1];
  const float* Wa  = (const float*)d_in[2];
  const float* ba  = (const float*)d_in[3];
  const float* Wb  = (const float*)d_in[4];
  const float* bb  = (const float*)d_in[5];
  const float* W1  = (const float*)d_in[6];
  const float* b1  = (const float*)d_in[7];
  const float* W2  = (const float*)d_in[8];
  const float* b2  = (const float*)d_in[9];
  float* out = (float*)d_out;
  char* ws = (char*)d_ws;

  float* dynW = (float*)(ws + 0);                          // 384 KiB
  float* dynB = (float*)(ws + 393216);                     // 128 KiB
  unsigned short* W1p = (unsigned short*)(ws + 524288);    // 512 KiB (packed)
  unsigned short* W2p = (unsigned short*)(ws + 1048576);   // 96 KiB (packed)
  if (ws_size < 1179648ull) return;                        // ~1.2 MB needed

  const int smem_bytes = 78112;  // stage/x3b 12544 + xt 65536 + red 32
  (void)hipFuncSetAttribute((const void*)k_fused9,
                            hipFuncAttributeMaxDynamicSharedMemorySize,
                            smem_bytes);

  k_prep<<<512, 256, 0, stream>>>(emb, Wa, ba, Wb, bb, W1, W2,
                                  dynW, dynB, W1p, W2p, out);
  k_fused9<<<dim3(34, 64), 512, smem_bytes, stream>>>(h, W1p, b1, W2p, b2,
                                                      dynW, dynB, out);
}